// Round 3
// baseline (700.085 us; speedup 1.0000x reference)
//
#include <hip/hip_runtime.h>
#include <hip/hip_bf16.h>

// LSTM decoder: 12 steps, batch 32768, hidden 256, input 64, teacher forcing = 1.
// Strategy: batch rows are independent across the whole recurrence -> one
// persistent block per 128 rows (256 blocks = 256 CUs). h in double-buffered
// LDS (bf16), c in registers (MFMA fragment layout), W packed bf16 streamed
// from L2. gates = [h|x] @ W^T via mfma_f32_16x16x32_bf16, fp32 accum,
// nonlinearities + c update in fp32.

#define PRED_LEN 12
#define BATCH    32768
#define HID      256
#define IDIM     64
#define KTOT     320      // 256 (h) + 64 (x)
#define G4       1024     // 4*HID gate columns
#define BROWS    128      // batch rows per block
#define HSTR     264      // padded bf16 row stride for h in LDS (quad-stride 1 -> conflict-free b128)
#define XSTR     72       // padded bf16 row stride for x in LDS

#define LDS_H_BYTES (2 * BROWS * HSTR * 2)   // 135168
#define LDS_X_BYTES (BROWS * XSTR * 2)       // 18432
#define DYN_LDS     (LDS_H_BYTES + LDS_X_BYTES) // 153600

typedef short s16x8 __attribute__((ext_vector_type(8)));  // 8 x bf16 (MFMA frag)
typedef short s16x4 __attribute__((ext_vector_type(4)));
typedef float f32x4 __attribute__((ext_vector_type(4)));  // MFMA accum frag

static __device__ __forceinline__ float sigmoid_f(float x) {
    return 1.0f / (1.0f + __expf(-x));
}
static __device__ __forceinline__ float tanh_f(float x) {
    // tanh(x) = 1 - 2/(exp(2x)+1); saturates correctly for large |x|
    return 1.0f - 2.0f / (__expf(2.0f * x) + 1.0f);
}
static __device__ __forceinline__ unsigned short f2bf(float x) {
    __hip_bfloat16 h = __float2bfloat16(x);
    return *reinterpret_cast<unsigned short*>(&h);
}
static __device__ __forceinline__ float bf2f(unsigned short u) {
    __hip_bfloat16 h = *reinterpret_cast<__hip_bfloat16*>(&u);
    return __bfloat162float(h);
}

// Pack W = [W_hh | W_ih] as bf16 row-major [1024][320]; bcomb = b_ih + b_hh.
__global__ void prep_kernel(const float* __restrict__ W_ih,
                            const float* __restrict__ W_hh,
                            const float* __restrict__ b_ih,
                            const float* __restrict__ b_hh,
                            unsigned short* __restrict__ Wp,
                            float* __restrict__ bcomb) {
    int gid = blockIdx.x * 256 + threadIdx.x;
    if (gid < G4 * KTOT) {
        int n = gid / KTOT;
        int k = gid - n * KTOT;
        float v = (k < HID) ? W_hh[n * HID + k] : W_ih[n * IDIM + (k - HID)];
        Wp[gid] = f2bf(v);
    }
    if (gid < G4) bcomb[gid] = b_ih[gid] + b_hh[gid];
}

__global__ __launch_bounds__(512, 2) void lstm_kernel(
    const float* __restrict__ gr,      // (13, B, 2)
    const float* __restrict__ h0g,     // (B, 256)
    const unsigned short* __restrict__ Wp,   // (1024, 320) bf16
    const float* __restrict__ bcomb,   // (1024,)
    const float* __restrict__ W_hp,    // (2, 256)
    const float* __restrict__ b_hp,    // (2,)
    const float* __restrict__ W_emb,   // (64, 2)
    const float* __restrict__ b_emb,   // (64,)
    float* __restrict__ out)           // (12, B, 2)
{
    extern __shared__ unsigned short smem[];
    unsigned short* hb0 = smem;                        // [BROWS][HSTR]
    unsigned short* hb1 = smem + BROWS * HSTR;
    unsigned short* xb  = smem + 2 * BROWS * HSTR;     // [BROWS][XSTR]

    __shared__ float sWe0[IDIM], sWe1[IDIM], sBe[IDIM];
    __shared__ float sWhp[2 * HID];

    const int tid  = threadIdx.x;
    const int wave = tid >> 6;
    const int lane = tid & 63;
    const int l15  = lane & 15;
    const int lq   = lane >> 4;
    const int row0 = blockIdx.x * BROWS;

    // cache small constants in LDS
    if (tid < IDIM) {
        sWe0[tid] = W_emb[tid * 2 + 0];
        sWe1[tid] = W_emb[tid * 2 + 1];
        sBe[tid]  = b_emb[tid];
    }
    sWhp[tid] = W_hp[tid];   // blockDim 512 == 2*HID

    const float bhp0 = b_hp[0];
    const float bhp1 = b_hp[1];

    // per-lane combined gate biases: col = g*256 + ch*128 + wave*16 + l15
    float bias[2][4];
#pragma unroll
    for (int ch = 0; ch < 2; ++ch)
#pragma unroll
        for (int g = 0; g < 4; ++g)
            bias[ch][g] = bcomb[g * HID + ch * 128 + wave * 16 + l15];

    // stage h0 (fp32 global -> bf16 LDS hb0)
#pragma unroll
    for (int j = 0; j < 16; ++j) {
        int idx = j * 2048 + tid * 4;                 // 0..32764
        const float4 v = *reinterpret_cast<const float4*>(&h0g[row0 * HID + idx]);
        int r = idx >> 8;
        int c = idx & 255;
        s16x4 pk;
        pk[0] = (short)f2bf(v.x); pk[1] = (short)f2bf(v.y);
        pk[2] = (short)f2bf(v.z); pk[3] = (short)f2bf(v.w);
        *reinterpret_cast<s16x4*>(&hb0[r * HSTR + c]) = pk;
    }

    // inline embedding: x[t] = gr[t+1] @ W_emb^T + b_emb  -> bf16 LDS
    auto stage_x = [&](int tt) {
        const int rr = tid >> 2;
        const int d0 = (tid & 3) * 16;
        const float2 g2 = *reinterpret_cast<const float2*>(
            &gr[(((size_t)(tt + 1)) * BATCH + row0 + rr) * 2]);
        s16x8 v0, v1;
#pragma unroll
        for (int e = 0; e < 8; ++e) {
            int d = d0 + e;
            v0[e] = (short)f2bf(g2.x * sWe0[d] + g2.y * sWe1[d] + sBe[d]);
        }
#pragma unroll
        for (int e = 0; e < 8; ++e) {
            int d = d0 + 8 + e;
            v1[e] = (short)f2bf(g2.x * sWe0[d] + g2.y * sWe1[d] + sBe[d]);
        }
        *reinterpret_cast<s16x8*>(&xb[rr * XSTR + d0])     = v0;
        *reinterpret_cast<s16x8*>(&xb[rr * XSTR + d0 + 8]) = v1;
    };

    __syncthreads();      // sWe*/h0 staging visible
    stage_x(0);
    __syncthreads();

    // persistent cell state, fp32, in registers (MFMA C/D fragment layout)
    float cst[2][8][4];
#pragma unroll
    for (int ch = 0; ch < 2; ++ch)
#pragma unroll
        for (int m = 0; m < 8; ++m)
#pragma unroll
            for (int r = 0; r < 4; ++r) cst[ch][m][r] = 0.0f;

    unsigned short* hread  = hb0;
    unsigned short* hwrite = hb1;

    for (int t = 0; t < PRED_LEN; ++t) {
        // gates = [h|x] @ W^T ; each wave owns 16 hidden units per chunk
#pragma unroll
        for (int ch = 0; ch < 2; ++ch) {
            const int nbase = ch * 128 + wave * 16;
            f32x4 acc[8][4];
#pragma unroll
            for (int m = 0; m < 8; ++m)
#pragma unroll
                for (int g = 0; g < 4; ++g)
                    acc[m][g] = (f32x4){0.f, 0.f, 0.f, 0.f};

#pragma unroll
            for (int kf = 0; kf < 10; ++kf) {
                const int k0   = kf * 32;
                const int koff = k0 + lq * 8;
                s16x8 bfr[4];
#pragma unroll
                for (int g = 0; g < 4; ++g)
                    bfr[g] = *reinterpret_cast<const s16x8*>(
                        &Wp[(size_t)(g * HID + nbase + l15) * KTOT + koff]);
#pragma unroll
                for (int m = 0; m < 8; ++m) {
                    s16x8 afr;
                    if (k0 < 256)
                        afr = *reinterpret_cast<const s16x8*>(
                            &hread[(m * 16 + l15) * HSTR + koff]);
                    else
                        afr = *reinterpret_cast<const s16x8*>(
                            &xb[(m * 16 + l15) * XSTR + (koff - 256)]);
#pragma unroll
                    for (int g = 0; g < 4; ++g)
                        acc[m][g] = __builtin_amdgcn_mfma_f32_16x16x32_bf16(
                            afr, bfr[g], acc[m][g], 0, 0, 0);
                }
            }

            // LSTM cell update; i/f/g/o are same lane/reg across the 4 N-frags
#pragma unroll
            for (int m = 0; m < 8; ++m) {
#pragma unroll
                for (int r = 0; r < 4; ++r) {
                    float iv = acc[m][0][r] + bias[ch][0];
                    float fv = acc[m][1][r] + bias[ch][1];
                    float gv = acc[m][2][r] + bias[ch][2];
                    float ov = acc[m][3][r] + bias[ch][3];
                    float cn = sigmoid_f(fv) * cst[ch][m][r] + sigmoid_f(iv) * tanh_f(gv);
                    cst[ch][m][r] = cn;
                    float hn = sigmoid_f(ov) * tanh_f(cn);
                    hwrite[(m * 16 + lq * 4 + r) * HSTR + nbase + l15] = f2bf(hn);
                }
            }
        }
        __syncthreads();   // h_new complete; old h/x reads complete

        // out[t] = h_new @ W_hp^T + b_hp   (4 threads per row, shuffle-reduce)
        {
            const int rr = tid >> 2;
            const int q  = tid & 3;
            const unsigned short* hrow = &hwrite[rr * HSTR + q * 64];
            float s0 = 0.f, s1 = 0.f;
#pragma unroll
            for (int jj = 0; jj < 8; ++jj) {
                s16x8 hv = *reinterpret_cast<const s16x8*>(&hrow[jj * 8]);
#pragma unroll
                for (int e = 0; e < 8; ++e) {
                    float hf = bf2f((unsigned short)hv[e]);
                    int n = q * 64 + jj * 8 + e;
                    s0 += hf * sWhp[n];
                    s1 += hf * sWhp[HID + n];
                }
            }
            s0 += __shfl_xor(s0, 1); s0 += __shfl_xor(s0, 2);
            s1 += __shfl_xor(s1, 1); s1 += __shfl_xor(s1, 2);
            if (q == 0) {
                float2 o2 = make_float2(s0 + bhp0, s1 + bhp1);
                *reinterpret_cast<float2*>(&out[((size_t)t * BATCH + row0 + rr) * 2]) = o2;
            }
        }

        if (t + 1 < PRED_LEN) stage_x(t + 1);
        __syncthreads();   // x[t+1] staged; h_new reads (out proj) complete

        unsigned short* tmp = hread; hread = hwrite; hwrite = tmp;
    }
}

extern "C" void kernel_launch(void* const* d_in, const int* in_sizes, int n_in,
                              void* d_out, int out_size, void* d_ws, size_t ws_size,
                              hipStream_t stream) {
    const float* gr    = (const float*)d_in[0];
    const float* h0    = (const float*)d_in[1];
    const float* W_ih  = (const float*)d_in[2];
    const float* W_hh  = (const float*)d_in[3];
    const float* b_ih  = (const float*)d_in[4];
    const float* b_hh  = (const float*)d_in[5];
    const float* W_hp  = (const float*)d_in[6];
    const float* b_hp  = (const float*)d_in[7];
    const float* W_emb = (const float*)d_in[8];
    const float* b_emb = (const float*)d_in[9];
    float* out = (float*)d_out;

    unsigned short* Wp = (unsigned short*)d_ws;
    float* bcomb = (float*)((char*)d_ws + (size_t)G4 * KTOT * sizeof(unsigned short));

    prep_kernel<<<(G4 * KTOT) / 256, 256, 0, stream>>>(W_ih, W_hh, b_ih, b_hh, Wp, bcomb);

    // dynamic LDS 153600 B > 64 KB default: opt in (benign if unnecessary)
    (void)hipFuncSetAttribute((const void*)lstm_kernel,
                              hipFuncAttributeMaxDynamicSharedMemorySize, DYN_LDS);

    lstm_kernel<<<BATCH / BROWS, 512, DYN_LDS, stream>>>(
        gr, h0, Wp, bcomb, W_hp, b_hp, W_emb, b_emb, out);
}